// Round 10
// baseline (199.282 us; speedup 1.0000x reference)
//
#include <hip/hip_runtime.h>

// ---------------- types & helpers ----------------
typedef __attribute__((ext_vector_type(8))) short bf16x8;
typedef __attribute__((ext_vector_type(4))) float f32x4;
typedef __attribute__((ext_vector_type(4))) unsigned uint32x4;

#define MFMA32(a, b, c) __builtin_amdgcn_mfma_f32_16x16x32_bf16((a), (b), (c), 0, 0, 0)

__device__ __forceinline__ unsigned short f2bf(float f) {
  unsigned u = __builtin_bit_cast(unsigned, f);
  u += 0x7fffu + ((u >> 16) & 1u);   // RNE
  return (unsigned short)(u >> 16);
}
__device__ __forceinline__ unsigned pack2(float a, float b) {
  return (unsigned)f2bf(a) | ((unsigned)f2bf(b) << 16);
}
// truncating pack of two fp32 -> bf16x2 in ONE v_perm_b32 (bias cancels in
// softmax normalization; values are non-negative O(1))
__device__ __forceinline__ unsigned pack2t(float lo, float hi) {
  return __builtin_amdgcn_perm(__builtin_bit_cast(unsigned, hi),
                               __builtin_bit_cast(unsigned, lo), 0x07060302u);
}
// async global->LDS, 16B per lane; LDS dest = wave-uniform base + lane*16
__device__ __forceinline__ void gl_lds16(const unsigned short* g, unsigned short* l) {
  __builtin_amdgcn_global_load_lds(
      (const __attribute__((address_space(1))) unsigned int*)(g),
      (__attribute__((address_space(3))) unsigned int*)(l), 16, 0, 0);
}

// Problem constants: B=2, T=2048, C=1024, H=16, D=64, 3C=3072, M=B*T=4096
// Q is stored pre-scaled by 0.125 * log2(e) so attention uses exp2 directly.
#define QSCALE 0.18033688011112042f

// ---------------- fused prep kernel ----------------
// regions by blockIdx.x:
//  [0,2048)    : x fp32 -> xb bf16 (8 elems/thread)
//  [2048,2816) : Wqkv [1024][3072] -> wqt [3072][1024] bf16
//  [2816,3072) : Wo   [1024][1024] -> wot [1024][1024] bf16 (transposed)
__global__ __launch_bounds__(256) void prep_kernel(
    const float* __restrict__ x, const float* __restrict__ Wqkv,
    const float* __restrict__ Wo, unsigned short* __restrict__ xb,
    unsigned short* __restrict__ wqt, unsigned short* __restrict__ wot) {
  __shared__ unsigned short Tl[64][72];
  const int bid = blockIdx.x, tid = threadIdx.x;
  if (bid < 2048) {
    int i = (bid * 256 + tid) * 8;
    float4 a = *(const float4*)(x + i);
    float4 b = *(const float4*)(x + i + 4);
    uint4 w;
    w.x = pack2(a.x, a.y); w.y = pack2(a.z, a.w);
    w.z = pack2(b.x, b.y); w.w = pack2(b.z, b.w);
    *(uint4*)(xb + i) = w;
  } else {
    const float* src;
    unsigned short* dst;
    int N, kt, nt;
    if (bid < 2816) {
      int r = bid - 2048;
      src = Wqkv; dst = wqt; N = 3072;
      nt = (r % 48) * 64; kt = (r / 48) * 64;
    } else {
      int r = bid - 2816;
      src = Wo; dst = wot; N = 1024;
      nt = (r & 15) * 64; kt = (r >> 4) * 64;
    }
    const int rr = tid >> 2, cs = (tid & 3) * 16;
    const float* sp = src + (kt + rr) * N + nt + cs;
    uint4 w0, w1;
    {
      float4 a = *(const float4*)(sp), b = *(const float4*)(sp + 4);
      float4 c = *(const float4*)(sp + 8), d = *(const float4*)(sp + 12);
      w0.x = pack2(a.x, a.y); w0.y = pack2(a.z, a.w);
      w0.z = pack2(b.x, b.y); w0.w = pack2(b.z, b.w);
      w1.x = pack2(c.x, c.y); w1.y = pack2(c.z, c.w);
      w1.z = pack2(d.x, d.y); w1.w = pack2(d.z, d.w);
    }
    *(uint4*)(&Tl[rr][cs]) = w0;
    *(uint4*)(&Tl[rr][cs + 8]) = w1;
    __syncthreads();
    unsigned short tmp[16];
#pragma unroll
    for (int i = 0; i < 16; i++) tmp[i] = Tl[cs + i][rr];
    unsigned short* dp = dst + (nt + rr) * 1024 + kt + cs;
    *(uint4*)(dp) = *(const uint4*)(&tmp[0]);
    *(uint4*)(dp + 8) = *(const uint4*)(&tmp[8]);
  }
}

// ---------------- kernel 1: QKV GEMM (bf16 in) + RoPE + scatter ----------------
// xb[4096][1024] bf16, wt[3072][1024] bf16 (= Wqkv^T)
// -> qws/kws: [32][2048][64] bf16, vws: [32][64][2048] bf16 (key-permuted)
// 64x128 tile, BK=64, SINGLE-BARRIER ping-pong pipeline: prefetch tile t+1
// (async gl_lds16 to the other buffer) is issued right after the barrier and
// drains at the NEXT barrier, so its latency overlaps the compute of tile t.
__global__ __launch_bounds__(256, 3) void qkv_rope_kernel(
    const unsigned short* __restrict__ xb, const unsigned short* __restrict__ wt,
    unsigned short* __restrict__ qws, unsigned short* __restrict__ kws,
    unsigned short* __restrict__ vws) {
  __shared__ unsigned short Al[2][2 * 64 * 32];   // [buf][chunk][row][seg] 16KB
  __shared__ unsigned short Bl[2][2 * 128 * 32];  // 32KB

  const int tid = threadIdx.x;
  const int lane = tid & 63, wid = tid >> 6;
  const int quad = lane >> 4, col = lane & 15;
  const int wm = (wid >> 1) * 32, wn = (wid & 1) * 64;
  const int n0 = blockIdx.x * 128, m0 = blockIdx.y * 64;

  f32x4 acc[2][4] = {};
  const int srA = wid * 16 + (lane >> 2);                  // A rows: 16/wave
  const int srB = wid * 32 + (lane >> 2);                  // B rows: 32/wave
  const int gseg = ((lane & 3) ^ ((lane >> 3) & 3)) * 8;   // swizzled k-offset
  const int fsg = (quad ^ ((col >> 1) & 3)) * 8;           // fragment read offset

  auto stage = [&](int buf, int k0) {
#pragma unroll
    for (int c = 0; c < 2; c++) {
      const int kc = k0 + c * 32;
      gl_lds16(xb + (m0 + srA) * 1024 + kc + gseg, &Al[buf][c * 2048 + (wid * 16) * 32]);
      gl_lds16(wt + (n0 + srB) * 1024 + kc + gseg, &Bl[buf][c * 4096 + (wid * 32) * 32]);
      gl_lds16(wt + (n0 + srB + 16) * 1024 + kc + gseg,
               &Bl[buf][c * 4096 + (wid * 32 + 16) * 32]);
    }
  };

  stage(0, 0);
  for (int it = 0; it < 16; it++) {
    __syncthreads();                       // drains stage(it), issued 1 iter ago
    if (it + 1 < 16) stage((it + 1) & 1, (it + 1) * 64);  // in flight over compute
    const int buf = it & 1;
#pragma unroll
    for (int c = 0; c < 2; c++) {
      bf16x8 af[2], bfr[4];
#pragma unroll
      for (int i = 0; i < 2; i++)
        af[i] = *(const bf16x8*)(&Al[buf][c * 2048 + (wm + i * 16 + col) * 32 + fsg]);
#pragma unroll
      for (int j = 0; j < 4; j++)
        bfr[j] = *(const bf16x8*)(&Bl[buf][c * 4096 + (wn + j * 16 + col) * 32 + fsg]);
#pragma unroll
      for (int i = 0; i < 2; i++)
#pragma unroll
        for (int j = 0; j < 4; j++)
          acc[i][j] = MFMA32(af[i], bfr[j], acc[i][j]);
    }
  }

  // epilogue: RoPE on q/k (HW transcendentals), scatter
#pragma unroll
  for (int i = 0; i < 2; i++) {
#pragma unroll
    for (int j = 0; j < 4; j++) {
      const int nbase = n0 + wn + j * 16;   // wave-uniform
      const int region = nbase >> 10;       // 0=q, 1=k, 2=v
#pragma unroll
      for (int r = 0; r < 4; r++) {
        int m = m0 + wm + i * 16 + quad * 4 + r;
        int n = nbase + col;
        float val = acc[i][j][r];
        int nn = n & 1023, h = nn >> 6, d = nn & 63, b = m >> 11, t = m & 2047;
        if (region < 2) {
          float other = __shfl_xor(val, 1);  // partner dim (d^1)
          float invf = __expf(-(float)(d >> 1) * 0.28782313662425572f);  // ln(1e4)/32
          float ang = (float)t * invf;
          float sn, cs;
          __sincosf(ang, &sn, &cs);
          float rot = (d & 1) ? other : -other;
          val = fmaf(val, cs, rot * sn);
        }
        int bh = (b << 4) + h;
        if (region == 0) {
          qws[(bh * 2048 + t) * 64 + d] = f2bf(val * QSCALE);
        } else if (region == 1) {
          kws[(bh * 2048 + t) * 64 + d] = f2bf(val);
        } else {
          // permute key idx within 32-group to PV A-fragment physical order
          int tl = t & 31, g = t >> 5;
          int qd = (tl & 15) >> 2;
          int jj = (tl & 3) + ((tl & 16) ? 4 : 0);
          int tp = g * 32 + qd * 8 + jj;
          vws[(bh * 64 + d) * 2048 + tp] = f2bf(val);
        }
      }
    }
  }
}

// ---------------- kernel 2: causal flash attention, LDS-tiled ----------------
// One 64-row q-tile per block; grid (x=bh 32, y=qtile 32) = 1024 blocks =
// 4 blocks/CU. XCD swizzle: id%8 = bh%8 keeps each bh's K/V on one XCD's L2.
// Heavy-first dispatch. SINGLE-BARRIER ping-pong pipeline over 64-key tiles:
// Kl/Vl[2] alternate; prefetch of tile t+1 overlaps compute of tile t.
// Fixed-max softmax; S^T=K.Q^T register-identity into PV B-fragment.
__global__ __launch_bounds__(256, 4) void attn_kernel(
    const unsigned short* __restrict__ qws, const unsigned short* __restrict__ kws,
    const unsigned short* __restrict__ vws, unsigned short* __restrict__ aws) {
  __shared__ unsigned short Kl[2][64 * 64];  // [buf][key][dim] swizzled
  __shared__ unsigned short Vl[2][64 * 64];  // [buf][dim][key-permuted]

  const int tid = threadIdx.x;
  const int lane = tid & 63, wid = tid >> 6;
  const int quad = lane >> 4, col = lane & 15;
  const int bh = blockIdx.x;
  const unsigned short* qb = qws + bh * (2048 * 64);
  const unsigned short* kb = kws + bh * (2048 * 64);
  const unsigned short* vb = vws + bh * (64 * 2048);
  const int b = bh >> 4, h = bh & 15;

  const int sro = wid * 16 + (lane >> 3);                   // + 8 for 2nd slot
  const int sgs = ((lane & 7) ^ ((lane >> 3) & 7)) * 8;     // swizzled seg
  const int sA = (quad ^ (col & 7)) * 8;                    // frag read offset

  const int q0blk = (31 - (int)blockIdx.y) * 64;  // heavy-first
  const int qt = q0blk + wid * 16;
  const int qi = qt + col;
  const int qi_max = qt + 15;
  const int ntiles = (q0blk >> 6) + 1;            // 64-key tiles

  // Q as B-operand: lane holds Q[qt+col][chunk*32 + quad*8 + j]
  bf16x8 qf0 = *(const bf16x8*)(qb + (qt + col) * 64 + quad * 8);
  bf16x8 qf1 = *(const bf16x8*)(qb + (qt + col) * 64 + 32 + quad * 8);

  f32x4 o[4] = {};
  float lsum = 0.f;

  auto stage = [&](int buf, int kb0) {
    gl_lds16(kb + (kb0 + sro) * 64 + sgs, &Kl[buf][(wid * 16) * 64]);
    gl_lds16(kb + (kb0 + sro + 8) * 64 + sgs, &Kl[buf][(wid * 16 + 8) * 64]);
    gl_lds16(vb + sro * 2048 + kb0 + sgs, &Vl[buf][(wid * 16) * 64]);
    gl_lds16(vb + (sro + 8) * 2048 + kb0 + sgs, &Vl[buf][(wid * 16 + 8) * 64]);
  };

  stage(0, 0);
  for (int ti = 0; ti < ntiles; ti++) {
    __syncthreads();                      // drains stage(ti)
    if (ti + 1 < ntiles) stage((ti + 1) & 1, (ti + 1) * 64);
    const int u = ti & 1;
    const int kb0 = ti * 64;
    // every tile is at least partly unmasked for every wave (kb0 <= q0blk <= qt)
    const int smax = min(4, ((qi_max - kb0) >> 4) + 1);  // wave-uniform
    const bool diag = (kb0 + 64 > qt);                   // wave-uniform
    float p[16];
#pragma unroll
    for (int s = 0; s < 4; s++) {
      if (s < smax) {
        bf16x8 kfa = *(const bf16x8*)(&Kl[u][(s * 16 + col) * 64 + sA]);
        bf16x8 kfb = *(const bf16x8*)(&Kl[u][(s * 16 + col) * 64 + (sA ^ 32)]);
        f32x4 z = {0.f, 0.f, 0.f, 0.f};
        z = MFMA32(kfa, qf0, z);
        z = MFMA32(kfb, qf1, z);
        if (diag) {
#pragma unroll
          for (int r = 0; r < 4; r++)
            if (kb0 + s * 16 + quad * 4 + r > qi) z[r] = -1e30f;
        }
#pragma unroll
        for (int r = 0; r < 4; r++) {
          float e = exp2f(z[r]);
          p[s * 4 + r] = e;
          lsum += e;
        }
      } else {
#pragma unroll
        for (int r = 0; r < 4; r++) p[s * 4 + r] = 0.f;
      }
    }
    // P^T pack via v_perm truncation
    uint32x4 u0;
    u0[0] = pack2t(p[0], p[1]);   u0[1] = pack2t(p[2], p[3]);
    u0[2] = pack2t(p[4], p[5]);   u0[3] = pack2t(p[6], p[7]);
    bf16x8 pf0 = __builtin_bit_cast(bf16x8, u0);
#pragma unroll
    for (int dt = 0; dt < 4; dt++) {
      bf16x8 vfa = *(const bf16x8*)(&Vl[u][(dt * 16 + col) * 64 + sA]);
      o[dt] = MFMA32(vfa, pf0, o[dt]);
    }
    if (smax > 2) {
      uint32x4 u1;
      u1[0] = pack2t(p[8], p[9]);   u1[1] = pack2t(p[10], p[11]);
      u1[2] = pack2t(p[12], p[13]); u1[3] = pack2t(p[14], p[15]);
      bf16x8 pf1 = __builtin_bit_cast(bf16x8, u1);
#pragma unroll
      for (int dt = 0; dt < 4; dt++) {
        bf16x8 vfb = *(const bf16x8*)(&Vl[u][(dt * 16 + col) * 64 + (sA ^ 32)]);
        o[dt] = MFMA32(vfb, pf1, o[dt]);
      }
    }
  }

  lsum += __shfl_xor(lsum, 16);
  lsum += __shfl_xor(lsum, 32);
  float inv = 1.0f / lsum;
#pragma unroll
  for (int dt = 0; dt < 4; dt++)
#pragma unroll
    for (int r = 0; r < 4; r++) {
      int d = dt * 16 + quad * 4 + r;
      aws[(b * 2048 + qt + col) * 1024 + h * 64 + d] = f2bf(o[dt][r] * inv);
    }
}

// ---------------- kernel 3: output projection + bias ----------------
// aws[4096][1024] bf16 @ wot[1024][1024] bf16 (=Wo^T) + bo -> out fp32
// 64x128 tiles, BK=64, single-barrier ping-pong pipeline (as kernel 1).
__global__ __launch_bounds__(256, 3) void out_proj_kernel(
    const unsigned short* __restrict__ attn, const unsigned short* __restrict__ wot,
    const float* __restrict__ bo, float* __restrict__ out) {
  __shared__ unsigned short Al[2][2 * 64 * 32];
  __shared__ unsigned short Bl[2][2 * 128 * 32];

  const int tid = threadIdx.x;
  const int lane = tid & 63, wid = tid >> 6;
  const int quad = lane >> 4, col = lane & 15;
  const int wm = (wid >> 1) * 32, wn = (wid & 1) * 64;
  const int n0 = blockIdx.x * 128, m0 = blockIdx.y * 64;

  f32x4 acc[2][4] = {};
  const int sr = lane >> 2;
  const int gseg = ((lane & 3) ^ ((lane >> 3) & 3)) * 8;
  const int fsg = (quad ^ ((col >> 1) & 3)) * 8;

  auto stage = [&](int buf, int k0) {
#pragma unroll
    for (int c = 0; c < 2; c++) {
      const int kc = k0 + c * 32;
      gl_lds16(attn + (m0 + wid * 16 + sr) * 1024 + kc + gseg,
               &Al[buf][c * 2048 + (wid * 16) * 32]);
      gl_lds16(wot + (n0 + wid * 32 + sr) * 1024 + kc + gseg,
               &Bl[buf][c * 4096 + (wid * 32) * 32]);
      gl_lds16(wot + (n0 + wid * 32 + 16 + sr) * 1024 + kc + gseg,
               &Bl[buf][c * 4096 + (wid * 32 + 16) * 32]);
    }
  };

  stage(0, 0);
  for (int it = 0; it < 16; it++) {
    __syncthreads();
    if (it + 1 < 16) stage((it + 1) & 1, (it + 1) * 64);
    const int buf = it & 1;
#pragma unroll
    for (int c = 0; c < 2; c++) {
      bf16x8 af[2], bfr[4];
#pragma unroll
      for (int i = 0; i < 2; i++)
        af[i] = *(const bf16x8*)(&Al[buf][c * 2048 + (wm + i * 16 + col) * 32 + fsg]);
#pragma unroll
      for (int j = 0; j < 4; j++)
        bfr[j] = *(const bf16x8*)(&Bl[buf][c * 4096 + (wn + j * 16 + col) * 32 + fsg]);
#pragma unroll
      for (int i = 0; i < 2; i++)
#pragma unroll
        for (int j = 0; j < 4; j++)
          acc[i][j] = MFMA32(af[i], bfr[j], acc[i][j]);
    }
  }

#pragma unroll
  for (int i = 0; i < 2; i++)
#pragma unroll
    for (int j = 0; j < 4; j++)
#pragma unroll
      for (int r = 0; r < 4; r++) {
        int m = m0 + wm + i * 16 + quad * 4 + r;
        int n = n0 + wn + j * 16 + col;
        out[m * 1024 + n] = acc[i][j][r] + bo[n];
      }
}

// ---------------- launch ----------------
extern "C" void kernel_launch(void* const* d_in, const int* in_sizes, int n_in,
                              void* d_out, int out_size, void* d_ws, size_t ws_size,
                              hipStream_t stream) {
  const float* x = (const float*)d_in[0];
  const float* Wqkv = (const float*)d_in[1];
  const float* Wo = (const float*)d_in[2];
  const float* bo = (const float*)d_in[3];
  float* out = (float*)d_out;

  unsigned short* qws = (unsigned short*)d_ws;   // [32][2048][64]      8.4 MB
  unsigned short* kws = qws + 4194304;           // [32][2048][64]      8.4 MB
  unsigned short* vws = kws + 4194304;           // [32][64][2048]      8.4 MB
  unsigned short* xb  = vws + 4194304;           // [4096][1024] (dead after qkv)
  unsigned short* aws = xb;                      //   reused: attn out [4096][1024]
  unsigned short* wqt = xb + 4194304;            // [3072][1024]        6.3 MB
  unsigned short* wot = wqt + 3145728;           // [1024][1024]        2.1 MB

  prep_kernel<<<3072, 256, 0, stream>>>(x, Wqkv, Wo, xb, wqt, wot);
  qkv_rope_kernel<<<dim3(24, 64), 256, 0, stream>>>(xb, wqt, qws, kws, vws);
  attn_kernel<<<dim3(32, 32), 256, 0, stream>>>(qws, kws, vws, aws);
  out_proj_kernel<<<dim3(8, 64), 256, 0, stream>>>(aws, wot, bo, out);
}

// Round 11
// 193.212 us; speedup vs baseline: 1.0314x; 1.0314x over previous
//
#include <hip/hip_runtime.h>

// ---------------- types & helpers ----------------
typedef __attribute__((ext_vector_type(8))) short bf16x8;
typedef __attribute__((ext_vector_type(4))) float f32x4;
typedef __attribute__((ext_vector_type(4))) unsigned uint32x4;

#define MFMA32(a, b, c) __builtin_amdgcn_mfma_f32_16x16x32_bf16((a), (b), (c), 0, 0, 0)

__device__ __forceinline__ unsigned short f2bf(float f) {
  unsigned u = __builtin_bit_cast(unsigned, f);
  u += 0x7fffu + ((u >> 16) & 1u);   // RNE
  return (unsigned short)(u >> 16);
}
__device__ __forceinline__ unsigned pack2(float a, float b) {
  return (unsigned)f2bf(a) | ((unsigned)f2bf(b) << 16);
}
// truncating pack of two fp32 -> bf16x2 in ONE v_perm_b32 (bias cancels in
// softmax normalization; values are non-negative O(1))
__device__ __forceinline__ unsigned pack2t(float lo, float hi) {
  return __builtin_amdgcn_perm(__builtin_bit_cast(unsigned, hi),
                               __builtin_bit_cast(unsigned, lo), 0x07060302u);
}
// async global->LDS, 16B per lane; LDS dest = wave-uniform base + lane*16
__device__ __forceinline__ void gl_lds16(const unsigned short* g, unsigned short* l) {
  __builtin_amdgcn_global_load_lds(
      (const __attribute__((address_space(1))) unsigned int*)(g),
      (__attribute__((address_space(3))) unsigned int*)(l), 16, 0, 0);
}

// Problem constants: B=2, T=2048, C=1024, H=16, D=64, 3C=3072, M=B*T=4096
// Q is stored pre-scaled by 0.125 * log2(e) so attention uses exp2 directly.
#define QSCALE 0.18033688011112042f

// ---------------- fused prep kernel ----------------
// regions by blockIdx.x:
//  [0,2048)    : x fp32 -> xb bf16 (8 elems/thread)
//  [2048,2816) : Wqkv [1024][3072] -> wqt [3072][1024] bf16
//  [2816,3072) : Wo   [1024][1024] -> wot [1024][1024] bf16 (transposed)
__global__ __launch_bounds__(256) void prep_kernel(
    const float* __restrict__ x, const float* __restrict__ Wqkv,
    const float* __restrict__ Wo, unsigned short* __restrict__ xb,
    unsigned short* __restrict__ wqt, unsigned short* __restrict__ wot) {
  __shared__ unsigned short Tl[64][72];
  const int bid = blockIdx.x, tid = threadIdx.x;
  if (bid < 2048) {
    int i = (bid * 256 + tid) * 8;
    float4 a = *(const float4*)(x + i);
    float4 b = *(const float4*)(x + i + 4);
    uint4 w;
    w.x = pack2(a.x, a.y); w.y = pack2(a.z, a.w);
    w.z = pack2(b.x, b.y); w.w = pack2(b.z, b.w);
    *(uint4*)(xb + i) = w;
  } else {
    const float* src;
    unsigned short* dst;
    int N, kt, nt;
    if (bid < 2816) {
      int r = bid - 2048;
      src = Wqkv; dst = wqt; N = 3072;
      nt = (r % 48) * 64; kt = (r / 48) * 64;
    } else {
      int r = bid - 2816;
      src = Wo; dst = wot; N = 1024;
      nt = (r & 15) * 64; kt = (r >> 4) * 64;
    }
    const int rr = tid >> 2, cs = (tid & 3) * 16;
    const float* sp = src + (kt + rr) * N + nt + cs;
    uint4 w0, w1;
    {
      float4 a = *(const float4*)(sp), b = *(const float4*)(sp + 4);
      float4 c = *(const float4*)(sp + 8), d = *(const float4*)(sp + 12);
      w0.x = pack2(a.x, a.y); w0.y = pack2(a.z, a.w);
      w0.z = pack2(b.x, b.y); w0.w = pack2(b.z, b.w);
      w1.x = pack2(c.x, c.y); w1.y = pack2(c.z, c.w);
      w1.z = pack2(d.x, d.y); w1.w = pack2(d.z, d.w);
    }
    *(uint4*)(&Tl[rr][cs]) = w0;
    *(uint4*)(&Tl[rr][cs + 8]) = w1;
    __syncthreads();
    unsigned short tmp[16];
#pragma unroll
    for (int i = 0; i < 16; i++) tmp[i] = Tl[cs + i][rr];
    unsigned short* dp = dst + (nt + rr) * 1024 + kt + cs;
    *(uint4*)(dp) = *(const uint4*)(&tmp[0]);
    *(uint4*)(dp + 8) = *(const uint4*)(&tmp[8]);
  }
}

// ---------------- kernel 1: QKV GEMM (bf16 in) + RoPE + scatter ----------------
// xb[4096][1024] bf16, wt[3072][1024] bf16 (= Wqkv^T)
// -> qws/kws: [32][2048][64] bf16, vws: [32][64][2048] bf16 (key-permuted)
// 64x64 tile, BK=64 (two 32-wide chunks), 2-barrier loop. Grid 48x64 = 3072
// blocks; LDS 16KB + low VGPR -> 8 resident blocks/CU (occupancy lever).
// XCD = x%8 (48%8==0): all blocks sharing a B-tile sit on one XCD's L2.
__global__ __launch_bounds__(256, 8) void qkv_rope_kernel(
    const unsigned short* __restrict__ xb, const unsigned short* __restrict__ wt,
    unsigned short* __restrict__ qws, unsigned short* __restrict__ kws,
    unsigned short* __restrict__ vws) {
  __shared__ unsigned short Al[2 * 64 * 32];  // [chunk][row][k-seg swizzled] 8KB
  __shared__ unsigned short Bl[2 * 64 * 32];  // 8KB

  const int tid = threadIdx.x;
  const int lane = tid & 63, wid = tid >> 6;
  const int quad = lane >> 4, col = lane & 15;
  const int wm = (wid >> 1) * 32, wn = (wid & 1) * 32;
  const int n0 = blockIdx.x * 64, m0 = blockIdx.y * 64;

  f32x4 acc[2][2] = {};
  const int sr = wid * 16 + (lane >> 2);                   // 16 rows/wave
  const int gseg = ((lane & 3) ^ ((lane >> 3) & 3)) * 8;   // swizzled k-offset
  const int fsg = (quad ^ ((col >> 1) & 3)) * 8;           // fragment read offset

  for (int k0 = 0; k0 < 1024; k0 += 64) {
#pragma unroll
    for (int c = 0; c < 2; c++) {
      const int kc = k0 + c * 32, lo = c * 2048;
      gl_lds16(xb + (m0 + sr) * 1024 + kc + gseg, Al + lo + (wid * 16) * 32);
      gl_lds16(wt + (n0 + sr) * 1024 + kc + gseg, Bl + lo + (wid * 16) * 32);
    }
    __syncthreads();

#pragma unroll
    for (int c = 0; c < 2; c++) {
      const int lo = c * 2048;
      bf16x8 af[2], bfr[2];
#pragma unroll
      for (int i = 0; i < 2; i++)
        af[i] = *(const bf16x8*)(&Al[lo + (wm + i * 16 + col) * 32 + fsg]);
#pragma unroll
      for (int j = 0; j < 2; j++)
        bfr[j] = *(const bf16x8*)(&Bl[lo + (wn + j * 16 + col) * 32 + fsg]);
#pragma unroll
      for (int i = 0; i < 2; i++)
#pragma unroll
        for (int j = 0; j < 2; j++)
          acc[i][j] = MFMA32(af[i], bfr[j], acc[i][j]);
    }
    __syncthreads();
  }

  // epilogue: RoPE on q/k (HW transcendentals), scatter
#pragma unroll
  for (int i = 0; i < 2; i++) {
#pragma unroll
    for (int j = 0; j < 2; j++) {
      const int nbase = n0 + wn + j * 16;   // wave-uniform
      const int region = nbase >> 10;       // 0=q, 1=k, 2=v
#pragma unroll
      for (int r = 0; r < 4; r++) {
        int m = m0 + wm + i * 16 + quad * 4 + r;
        int n = nbase + col;
        float val = acc[i][j][r];
        int nn = n & 1023, h = nn >> 6, d = nn & 63, b = m >> 11, t = m & 2047;
        if (region < 2) {
          float other = __shfl_xor(val, 1);  // partner dim (d^1)
          float invf = __expf(-(float)(d >> 1) * 0.28782313662425572f);  // ln(1e4)/32
          float ang = (float)t * invf;
          float sn, cs;
          __sincosf(ang, &sn, &cs);
          float rot = (d & 1) ? other : -other;
          val = fmaf(val, cs, rot * sn);
        }
        int bh = (b << 4) + h;
        if (region == 0) {
          qws[(bh * 2048 + t) * 64 + d] = f2bf(val * QSCALE);
        } else if (region == 1) {
          kws[(bh * 2048 + t) * 64 + d] = f2bf(val);
        } else {
          // permute key idx within 32-group to PV A-fragment physical order
          int tl = t & 31, g = t >> 5;
          int qd = (tl & 15) >> 2;
          int jj = (tl & 3) + ((tl & 16) ? 4 : 0);
          int tp = g * 32 + qd * 8 + jj;
          vws[(bh * 64 + d) * 2048 + tp] = f2bf(val);
        }
      }
    }
  }
}

// ---------------- kernel 2: causal flash attention, LDS-tiled ----------------
// One 64-row q-tile per block; grid (x=bh 32, y=qtile 32) = 1024 blocks =
// 4 blocks/CU (16 waves/CU) for latency hiding. XCD swizzle: id%8 = bh%8 so
// all q-tiles of one bh share an XCD (K/V L2-resident, 4 bh x 512KB = 2MB).
// Heavy-first: y=0 -> q0blk=1984 so long blocks launch first, light backfill.
// 4 waves x 16 q-rows; 128 keys per barrier-pair; wave-uniform skip of fully
// masked 16-key sub-tiles. Fixed-max softmax; S^T=K.Q^T register-identity.
__global__ __launch_bounds__(256, 4) void attn_kernel(
    const unsigned short* __restrict__ qws, const unsigned short* __restrict__ kws,
    const unsigned short* __restrict__ vws, unsigned short* __restrict__ aws) {
  __shared__ unsigned short Kl[2][64 * 64];  // [buf][key][dim] swizzled
  __shared__ unsigned short Vl[2][64 * 64];  // [buf][dim][key-permuted]

  const int tid = threadIdx.x;
  const int lane = tid & 63, wid = tid >> 6;
  const int quad = lane >> 4, col = lane & 15;
  const int bh = blockIdx.x;
  const unsigned short* qb = qws + bh * (2048 * 64);
  const unsigned short* kb = kws + bh * (2048 * 64);
  const unsigned short* vb = vws + bh * (64 * 2048);
  const int b = bh >> 4, h = bh & 15;

  const int sro = wid * 16 + (lane >> 3);                   // + 8 for 2nd slot
  const int sgs = ((lane & 7) ^ ((lane >> 3) & 7)) * 8;     // swizzled seg
  const int sA = (quad ^ (col & 7)) * 8;                    // frag read offset

  const int q0blk = (31 - (int)blockIdx.y) * 64;  // heavy-first
  const int qt = q0blk + wid * 16;
  const int qi = qt + col;
  const int qi_max = qt + 15;
  const int kend = q0blk + 64;

  // Q as B-operand: lane holds Q[qt+col][chunk*32 + quad*8 + j]
  bf16x8 qf0 = *(const bf16x8*)(qb + (qt + col) * 64 + quad * 8);
  bf16x8 qf1 = *(const bf16x8*)(qb + (qt + col) * 64 + 32 + quad * 8);

  f32x4 o[4] = {};
  float lsum = 0.f;

  for (int k0 = 0; k0 < kend; k0 += 128) {
    const int nsub = (kend - k0 > 64) ? 2 : 1;  // block-uniform
    for (int u = 0; u < nsub; u++) {
      const int kb0 = k0 + u * 64;
      gl_lds16(kb + (kb0 + sro) * 64 + sgs, Kl[u] + (wid * 16) * 64);
      gl_lds16(kb + (kb0 + sro + 8) * 64 + sgs, Kl[u] + (wid * 16 + 8) * 64);
      gl_lds16(vb + sro * 2048 + kb0 + sgs, Vl[u] + (wid * 16) * 64);
      gl_lds16(vb + (sro + 8) * 2048 + kb0 + sgs, Vl[u] + (wid * 16 + 8) * 64);
    }
    __syncthreads();

    for (int u = 0; u < nsub; u++) {
      const int kb0 = k0 + u * 64;
      if (kb0 > qi_max) break;  // wave-uniform: rest fully masked
      const int smax = min(4, ((qi_max - kb0) >> 4) + 1);  // wave-uniform
      const bool diag = (kb0 + 64 > qt);                   // wave-uniform
      float p[16];
#pragma unroll
      for (int s = 0; s < 4; s++) {
        if (s < smax) {
          bf16x8 kfa = *(const bf16x8*)(&Kl[u][(s * 16 + col) * 64 + sA]);
          bf16x8 kfb = *(const bf16x8*)(&Kl[u][(s * 16 + col) * 64 + (sA ^ 32)]);
          f32x4 z = {0.f, 0.f, 0.f, 0.f};
          z = MFMA32(kfa, qf0, z);
          z = MFMA32(kfb, qf1, z);
          if (diag) {
#pragma unroll
            for (int r = 0; r < 4; r++)
              if (kb0 + s * 16 + quad * 4 + r > qi) z[r] = -1e30f;
          }
#pragma unroll
          for (int r = 0; r < 4; r++) {
            float e = exp2f(z[r]);
            p[s * 4 + r] = e;
            lsum += e;
          }
        } else {
#pragma unroll
          for (int r = 0; r < 4; r++) p[s * 4 + r] = 0.f;
        }
      }
      // P^T pack via v_perm truncation
      uint32x4 u0;
      u0[0] = pack2t(p[0], p[1]);   u0[1] = pack2t(p[2], p[3]);
      u0[2] = pack2t(p[4], p[5]);   u0[3] = pack2t(p[6], p[7]);
      bf16x8 pf0 = __builtin_bit_cast(bf16x8, u0);
#pragma unroll
      for (int dt = 0; dt < 4; dt++) {
        bf16x8 vfa = *(const bf16x8*)(&Vl[u][(dt * 16 + col) * 64 + sA]);
        o[dt] = MFMA32(vfa, pf0, o[dt]);
      }
      if (smax > 2) {
        uint32x4 u1;
        u1[0] = pack2t(p[8], p[9]);   u1[1] = pack2t(p[10], p[11]);
        u1[2] = pack2t(p[12], p[13]); u1[3] = pack2t(p[14], p[15]);
        bf16x8 pf1 = __builtin_bit_cast(bf16x8, u1);
#pragma unroll
        for (int dt = 0; dt < 4; dt++) {
          bf16x8 vfb = *(const bf16x8*)(&Vl[u][(dt * 16 + col) * 64 + (sA ^ 32)]);
          o[dt] = MFMA32(vfb, pf1, o[dt]);
        }
      }
    }
    __syncthreads();
  }

  lsum += __shfl_xor(lsum, 16);
  lsum += __shfl_xor(lsum, 32);
  float inv = 1.0f / lsum;
#pragma unroll
  for (int dt = 0; dt < 4; dt++)
#pragma unroll
    for (int r = 0; r < 4; r++) {
      int d = dt * 16 + quad * 4 + r;
      aws[(b * 2048 + qt + col) * 1024 + h * 64 + d] = f2bf(o[dt][r] * inv);
    }
}

// ---------------- kernel 3: output projection + bias ----------------
// aws[4096][1024] bf16 @ wot[1024][1024] bf16 (=Wo^T) + bo -> out fp32
// 64x64 tiles, BK=64, 2-barrier loop; grid 16x64 = 1024 blocks, 16KB LDS ->
// 8 resident blocks/CU.
__global__ __launch_bounds__(256, 8) void out_proj_kernel(
    const unsigned short* __restrict__ attn, const unsigned short* __restrict__ wot,
    const float* __restrict__ bo, float* __restrict__ out) {
  __shared__ unsigned short Al[2 * 64 * 32];
  __shared__ unsigned short Bl[2 * 64 * 32];

  const int tid = threadIdx.x;
  const int lane = tid & 63, wid = tid >> 6;
  const int quad = lane >> 4, col = lane & 15;
  const int wm = (wid >> 1) * 32, wn = (wid & 1) * 32;
  const int n0 = blockIdx.x * 64, m0 = blockIdx.y * 64;

  f32x4 acc[2][2] = {};
  const int sr = wid * 16 + (lane >> 2);
  const int gseg = ((lane & 3) ^ ((lane >> 3) & 3)) * 8;
  const int fsg = (quad ^ ((col >> 1) & 3)) * 8;

  for (int k0 = 0; k0 < 1024; k0 += 64) {
#pragma unroll
    for (int c = 0; c < 2; c++) {
      const int kc = k0 + c * 32, lo = c * 2048;
      gl_lds16(attn + (m0 + sr) * 1024 + kc + gseg, Al + lo + (wid * 16) * 32);
      gl_lds16(wot + (n0 + sr) * 1024 + kc + gseg, Bl + lo + (wid * 16) * 32);
    }
    __syncthreads();

#pragma unroll
    for (int c = 0; c < 2; c++) {
      const int lo = c * 2048;
      bf16x8 af[2], bfr[2];
#pragma unroll
      for (int i = 0; i < 2; i++)
        af[i] = *(const bf16x8*)(&Al[lo + (wm + i * 16 + col) * 32 + fsg]);
#pragma unroll
      for (int j = 0; j < 2; j++)
        bfr[j] = *(const bf16x8*)(&Bl[lo + (wn + j * 16 + col) * 32 + fsg]);
#pragma unroll
      for (int i = 0; i < 2; i++)
#pragma unroll
        for (int j = 0; j < 2; j++)
          acc[i][j] = MFMA32(af[i], bfr[j], acc[i][j]);
    }
    __syncthreads();
  }

#pragma unroll
  for (int i = 0; i < 2; i++)
#pragma unroll
    for (int j = 0; j < 2; j++)
#pragma unroll
      for (int r = 0; r < 4; r++) {
        int m = m0 + wm + i * 16 + quad * 4 + r;
        int n = n0 + wn + j * 16 + col;
        out[m * 1024 + n] = acc[i][j][r] + bo[n];
      }
}

// ---------------- launch ----------------
extern "C" void kernel_launch(void* const* d_in, const int* in_sizes, int n_in,
                              void* d_out, int out_size, void* d_ws, size_t ws_size,
                              hipStream_t stream) {
  const float* x = (const float*)d_in[0];
  const float* Wqkv = (const float*)d_in[1];
  const float* Wo = (const float*)d_in[2];
  const float* bo = (const float*)d_in[3];
  float* out = (float*)d_out;

  unsigned short* qws = (unsigned short*)d_ws;   // [32][2048][64]      8.4 MB
  unsigned short* kws = qws + 4194304;           // [32][2048][64]      8.4 MB
  unsigned short* vws = kws + 4194304;           // [32][64][2048]      8.4 MB
  unsigned short* xb  = vws + 4194304;           // [4096][1024] (dead after qkv)
  unsigned short* aws = xb;                      //   reused: attn out [4096][1024]
  unsigned short* wqt = xb + 4194304;            // [3072][1024]        6.3 MB
  unsigned short* wot = wqt + 3145728;           // [1024][1024]        2.1 MB

  prep_kernel<<<3072, 256, 0, stream>>>(x, Wqkv, Wo, xb, wqt, wot);
  qkv_rope_kernel<<<dim3(48, 64), 256, 0, stream>>>(xb, wqt, qws, kws, vws);
  attn_kernel<<<dim3(32, 32), 256, 0, stream>>>(qws, kws, vws, aws);
  out_proj_kernel<<<dim3(16, 64), 256, 0, stream>>>(aws, wot, bo, out);
}

// Round 12
// 186.092 us; speedup vs baseline: 1.0709x; 1.0383x over previous
//
#include <hip/hip_runtime.h>

// ---------------- types & helpers ----------------
typedef __attribute__((ext_vector_type(8))) short bf16x8;
typedef __attribute__((ext_vector_type(4))) float f32x4;
typedef __attribute__((ext_vector_type(4))) unsigned uint32x4;

#define MFMA32(a, b, c) __builtin_amdgcn_mfma_f32_16x16x32_bf16((a), (b), (c), 0, 0, 0)

__device__ __forceinline__ unsigned short f2bf(float f) {
  unsigned u = __builtin_bit_cast(unsigned, f);
  u += 0x7fffu + ((u >> 16) & 1u);   // RNE
  return (unsigned short)(u >> 16);
}
__device__ __forceinline__ unsigned pack2(float a, float b) {
  return (unsigned)f2bf(a) | ((unsigned)f2bf(b) << 16);
}
// truncating pack of two fp32 -> bf16x2 in ONE v_perm_b32 (bias cancels in
// softmax normalization; values are non-negative O(1))
__device__ __forceinline__ unsigned pack2t(float lo, float hi) {
  return __builtin_amdgcn_perm(__builtin_bit_cast(unsigned, hi),
                               __builtin_bit_cast(unsigned, lo), 0x07060302u);
}
// async global->LDS, 16B per lane; LDS dest = wave-uniform base + lane*16
__device__ __forceinline__ void gl_lds16(const unsigned short* g, unsigned short* l) {
  __builtin_amdgcn_global_load_lds(
      (const __attribute__((address_space(1))) unsigned int*)(g),
      (__attribute__((address_space(3))) unsigned int*)(l), 16, 0, 0);
}

// Problem constants: B=2, T=2048, C=1024, H=16, D=64, 3C=3072, M=B*T=4096
// Q is stored pre-scaled by 0.125 * log2(e) so attention uses exp2 directly.
#define QSCALE 0.18033688011112042f

// ---------------- fused prep kernel ----------------
// regions by blockIdx.x:
//  [0,2048)    : x fp32 -> xb bf16 (8 elems/thread)
//  [2048,2816) : Wqkv [1024][3072] -> wqt [3072][1024] bf16
//  [2816,3072) : Wo   [1024][1024] -> wot [1024][1024] bf16 (transposed)
__global__ __launch_bounds__(256) void prep_kernel(
    const float* __restrict__ x, const float* __restrict__ Wqkv,
    const float* __restrict__ Wo, unsigned short* __restrict__ xb,
    unsigned short* __restrict__ wqt, unsigned short* __restrict__ wot) {
  __shared__ unsigned short Tl[64][72];
  const int bid = blockIdx.x, tid = threadIdx.x;
  if (bid < 2048) {
    int i = (bid * 256 + tid) * 8;
    float4 a = *(const float4*)(x + i);
    float4 b = *(const float4*)(x + i + 4);
    uint4 w;
    w.x = pack2(a.x, a.y); w.y = pack2(a.z, a.w);
    w.z = pack2(b.x, b.y); w.w = pack2(b.z, b.w);
    *(uint4*)(xb + i) = w;
  } else {
    const float* src;
    unsigned short* dst;
    int N, kt, nt;
    if (bid < 2816) {
      int r = bid - 2048;
      src = Wqkv; dst = wqt; N = 3072;
      nt = (r % 48) * 64; kt = (r / 48) * 64;
    } else {
      int r = bid - 2816;
      src = Wo; dst = wot; N = 1024;
      nt = (r & 15) * 64; kt = (r >> 4) * 64;
    }
    const int rr = tid >> 2, cs = (tid & 3) * 16;
    const float* sp = src + (kt + rr) * N + nt + cs;
    uint4 w0, w1;
    {
      float4 a = *(const float4*)(sp), b = *(const float4*)(sp + 4);
      float4 c = *(const float4*)(sp + 8), d = *(const float4*)(sp + 12);
      w0.x = pack2(a.x, a.y); w0.y = pack2(a.z, a.w);
      w0.z = pack2(b.x, b.y); w0.w = pack2(b.z, b.w);
      w1.x = pack2(c.x, c.y); w1.y = pack2(c.z, c.w);
      w1.z = pack2(d.x, d.y); w1.w = pack2(d.z, d.w);
    }
    *(uint4*)(&Tl[rr][cs]) = w0;
    *(uint4*)(&Tl[rr][cs + 8]) = w1;
    __syncthreads();
    unsigned short tmp[16];
#pragma unroll
    for (int i = 0; i < 16; i++) tmp[i] = Tl[cs + i][rr];
    unsigned short* dp = dst + (nt + rr) * 1024 + kt + cs;
    *(uint4*)(dp) = *(const uint4*)(&tmp[0]);
    *(uint4*)(dp + 8) = *(const uint4*)(&tmp[8]);
  }
}

// ---------------- kernel 1: QKV GEMM (bf16 in) + RoPE + scatter ----------------
// xb[4096][1024] bf16, wt[3072][1024] bf16 (= Wqkv^T)
// -> qws/kws: [32][2048][64] bf16, vws: [32][64][2048] bf16 (key-permuted)
// R9 config (measured best of {128x128@3, 64x128@6, 64x64@8 blocks/CU}):
// 64x128 tile, BK=64 as two stacked 32-wide half-tiles, grid 24x64 = 1536
// blocks (~6/CU).
__global__ __launch_bounds__(256, 6) void qkv_rope_kernel(
    const unsigned short* __restrict__ xb, const unsigned short* __restrict__ wt,
    unsigned short* __restrict__ qws, unsigned short* __restrict__ kws,
    unsigned short* __restrict__ vws) {
  __shared__ unsigned short Al[2 * 64 * 32];   // [chunk][row][k-seg swizzled] 8KB
  __shared__ unsigned short Bl[2 * 128 * 32];  // 16KB

  const int tid = threadIdx.x;
  const int lane = tid & 63, wid = tid >> 6;
  const int quad = lane >> 4, col = lane & 15;
  const int wm = (wid >> 1) * 32, wn = (wid & 1) * 64;
  const int n0 = blockIdx.x * 128, m0 = blockIdx.y * 64;

  f32x4 acc[2][4] = {};
  const int srA = wid * 16 + (lane >> 2);                  // A rows: 16/wave
  const int srB = wid * 32 + (lane >> 2);                  // B rows: 32/wave
  const int gseg = ((lane & 3) ^ ((lane >> 3) & 3)) * 8;   // swizzled k-offset
  const int fsg = (quad ^ ((col >> 1) & 3)) * 8;           // fragment read offset

  for (int k0 = 0; k0 < 1024; k0 += 64) {
#pragma unroll
    for (int c = 0; c < 2; c++) {
      const int kc = k0 + c * 32;
      gl_lds16(xb + (m0 + srA) * 1024 + kc + gseg, Al + c * 2048 + (wid * 16) * 32);
      gl_lds16(wt + (n0 + srB) * 1024 + kc + gseg, Bl + c * 4096 + (wid * 32) * 32);
      gl_lds16(wt + (n0 + srB + 16) * 1024 + kc + gseg,
               Bl + c * 4096 + (wid * 32 + 16) * 32);
    }
    __syncthreads();

#pragma unroll
    for (int c = 0; c < 2; c++) {
      bf16x8 af[2], bfr[4];
#pragma unroll
      for (int i = 0; i < 2; i++)
        af[i] = *(const bf16x8*)(&Al[c * 2048 + (wm + i * 16 + col) * 32 + fsg]);
#pragma unroll
      for (int j = 0; j < 4; j++)
        bfr[j] = *(const bf16x8*)(&Bl[c * 4096 + (wn + j * 16 + col) * 32 + fsg]);
#pragma unroll
      for (int i = 0; i < 2; i++)
#pragma unroll
        for (int j = 0; j < 4; j++)
          acc[i][j] = MFMA32(af[i], bfr[j], acc[i][j]);
    }
    __syncthreads();
  }

  // epilogue: RoPE on q/k (HW transcendentals), scatter
#pragma unroll
  for (int i = 0; i < 2; i++) {
#pragma unroll
    for (int j = 0; j < 4; j++) {
      const int nbase = n0 + wn + j * 16;   // wave-uniform
      const int region = nbase >> 10;       // 0=q, 1=k, 2=v
#pragma unroll
      for (int r = 0; r < 4; r++) {
        int m = m0 + wm + i * 16 + quad * 4 + r;
        int n = nbase + col;
        float val = acc[i][j][r];
        int nn = n & 1023, h = nn >> 6, d = nn & 63, b = m >> 11, t = m & 2047;
        if (region < 2) {
          float other = __shfl_xor(val, 1);  // partner dim (d^1)
          float invf = __expf(-(float)(d >> 1) * 0.28782313662425572f);  // ln(1e4)/32
          float ang = (float)t * invf;
          float sn, cs;
          __sincosf(ang, &sn, &cs);
          float rot = (d & 1) ? other : -other;
          val = fmaf(val, cs, rot * sn);
        }
        int bh = (b << 4) + h;
        if (region == 0) {
          qws[(bh * 2048 + t) * 64 + d] = f2bf(val * QSCALE);
        } else if (region == 1) {
          kws[(bh * 2048 + t) * 64 + d] = f2bf(val);
        } else {
          // permute key idx within 32-group to PV A-fragment physical order
          int tl = t & 31, g = t >> 5;
          int qd = (tl & 15) >> 2;
          int jj = (tl & 3) + ((tl & 16) ? 4 : 0);
          int tp = g * 32 + qd * 8 + jj;
          vws[(bh * 64 + d) * 2048 + tp] = f2bf(val);
        }
      }
    }
  }
}

// ---------------- kernel 2: causal flash attention, LDS-tiled ----------------
// One 64-row q-tile per block; grid (x=bh 32, y=qtile 32) = 1024 blocks.
// lb(256,5): 32KB LDS x 5 = 160KB exactly -> 5 resident blocks/CU.
// XCD swizzle: id%8 = bh%8 so all q-tiles of one bh share an XCD (K/V
// L2-resident). Heavy-first: y=0 -> q0blk=1984.
// 4 waves x 16 q-rows; 128 keys per barrier-pair; wave-uniform skip of fully
// masked 16-key sub-tiles. Fixed-max softmax; S^T=K.Q^T register-identity.
__global__ __launch_bounds__(256, 5) void attn_kernel(
    const unsigned short* __restrict__ qws, const unsigned short* __restrict__ kws,
    const unsigned short* __restrict__ vws, unsigned short* __restrict__ aws) {
  __shared__ unsigned short Kl[2][64 * 64];  // [buf][key][dim] swizzled
  __shared__ unsigned short Vl[2][64 * 64];  // [buf][dim][key-permuted]

  const int tid = threadIdx.x;
  const int lane = tid & 63, wid = tid >> 6;
  const int quad = lane >> 4, col = lane & 15;
  const int bh = blockIdx.x;
  const unsigned short* qb = qws + bh * (2048 * 64);
  const unsigned short* kb = kws + bh * (2048 * 64);
  const unsigned short* vb = vws + bh * (64 * 2048);
  const int b = bh >> 4, h = bh & 15;

  const int sro = wid * 16 + (lane >> 3);                   // + 8 for 2nd slot
  const int sgs = ((lane & 7) ^ ((lane >> 3) & 7)) * 8;     // swizzled seg
  const int sA = (quad ^ (col & 7)) * 8;                    // frag read offset

  const int q0blk = (31 - (int)blockIdx.y) * 64;  // heavy-first
  const int qt = q0blk + wid * 16;
  const int qi = qt + col;
  const int qi_max = qt + 15;
  const int kend = q0blk + 64;

  // Q as B-operand: lane holds Q[qt+col][chunk*32 + quad*8 + j]
  bf16x8 qf0 = *(const bf16x8*)(qb + (qt + col) * 64 + quad * 8);
  bf16x8 qf1 = *(const bf16x8*)(qb + (qt + col) * 64 + 32 + quad * 8);

  f32x4 o[4] = {};
  float lsum = 0.f;

  for (int k0 = 0; k0 < kend; k0 += 128) {
    const int nsub = (kend - k0 > 64) ? 2 : 1;  // block-uniform
    for (int u = 0; u < nsub; u++) {
      const int kb0 = k0 + u * 64;
      gl_lds16(kb + (kb0 + sro) * 64 + sgs, Kl[u] + (wid * 16) * 64);
      gl_lds16(kb + (kb0 + sro + 8) * 64 + sgs, Kl[u] + (wid * 16 + 8) * 64);
      gl_lds16(vb + sro * 2048 + kb0 + sgs, Vl[u] + (wid * 16) * 64);
      gl_lds16(vb + (sro + 8) * 2048 + kb0 + sgs, Vl[u] + (wid * 16 + 8) * 64);
    }
    __syncthreads();

    for (int u = 0; u < nsub; u++) {
      const int kb0 = k0 + u * 64;
      if (kb0 > qi_max) break;  // wave-uniform: rest fully masked
      const int smax = min(4, ((qi_max - kb0) >> 4) + 1);  // wave-uniform
      const bool diag = (kb0 + 64 > qt);                   // wave-uniform
      float p[16];
#pragma unroll
      for (int s = 0; s < 4; s++) {
        if (s < smax) {
          bf16x8 kfa = *(const bf16x8*)(&Kl[u][(s * 16 + col) * 64 + sA]);
          bf16x8 kfb = *(const bf16x8*)(&Kl[u][(s * 16 + col) * 64 + (sA ^ 32)]);
          f32x4 z = {0.f, 0.f, 0.f, 0.f};
          z = MFMA32(kfa, qf0, z);
          z = MFMA32(kfb, qf1, z);
          if (diag) {
#pragma unroll
            for (int r = 0; r < 4; r++)
              if (kb0 + s * 16 + quad * 4 + r > qi) z[r] = -1e30f;
          }
#pragma unroll
          for (int r = 0; r < 4; r++) {
            float e = exp2f(z[r]);
            p[s * 4 + r] = e;
            lsum += e;
          }
        } else {
#pragma unroll
          for (int r = 0; r < 4; r++) p[s * 4 + r] = 0.f;
        }
      }
      // P^T pack via v_perm truncation
      uint32x4 u0;
      u0[0] = pack2t(p[0], p[1]);   u0[1] = pack2t(p[2], p[3]);
      u0[2] = pack2t(p[4], p[5]);   u0[3] = pack2t(p[6], p[7]);
      bf16x8 pf0 = __builtin_bit_cast(bf16x8, u0);
#pragma unroll
      for (int dt = 0; dt < 4; dt++) {
        bf16x8 vfa = *(const bf16x8*)(&Vl[u][(dt * 16 + col) * 64 + sA]);
        o[dt] = MFMA32(vfa, pf0, o[dt]);
      }
      if (smax > 2) {
        uint32x4 u1;
        u1[0] = pack2t(p[8], p[9]);   u1[1] = pack2t(p[10], p[11]);
        u1[2] = pack2t(p[12], p[13]); u1[3] = pack2t(p[14], p[15]);
        bf16x8 pf1 = __builtin_bit_cast(bf16x8, u1);
#pragma unroll
        for (int dt = 0; dt < 4; dt++) {
          bf16x8 vfb = *(const bf16x8*)(&Vl[u][(dt * 16 + col) * 64 + (sA ^ 32)]);
          o[dt] = MFMA32(vfb, pf1, o[dt]);
        }
      }
    }
    __syncthreads();
  }

  lsum += __shfl_xor(lsum, 16);
  lsum += __shfl_xor(lsum, 32);
  float inv = 1.0f / lsum;
#pragma unroll
  for (int dt = 0; dt < 4; dt++)
#pragma unroll
    for (int r = 0; r < 4; r++) {
      int d = dt * 16 + quad * 4 + r;
      aws[(b * 2048 + qt + col) * 1024 + h * 64 + d] = f2bf(o[dt][r] * inv);
    }
}

// ---------------- kernel 3: output projection + bias ----------------
// aws[4096][1024] bf16 @ wot[1024][1024] bf16 (=Wo^T) + bo -> out fp32
// 64x64 tiles, BK=64, 2-barrier loop; grid 16x64 = 1024 blocks, 16KB LDS ->
// 8 resident blocks/CU.
__global__ __launch_bounds__(256, 8) void out_proj_kernel(
    const unsigned short* __restrict__ attn, const unsigned short* __restrict__ wot,
    const float* __restrict__ bo, float* __restrict__ out) {
  __shared__ unsigned short Al[2 * 64 * 32];
  __shared__ unsigned short Bl[2 * 64 * 32];

  const int tid = threadIdx.x;
  const int lane = tid & 63, wid = tid >> 6;
  const int quad = lane >> 4, col = lane & 15;
  const int wm = (wid >> 1) * 32, wn = (wid & 1) * 32;
  const int n0 = blockIdx.x * 64, m0 = blockIdx.y * 64;

  f32x4 acc[2][2] = {};
  const int sr = wid * 16 + (lane >> 2);
  const int gseg = ((lane & 3) ^ ((lane >> 3) & 3)) * 8;
  const int fsg = (quad ^ ((col >> 1) & 3)) * 8;

  for (int k0 = 0; k0 < 1024; k0 += 64) {
#pragma unroll
    for (int c = 0; c < 2; c++) {
      const int kc = k0 + c * 32, lo = c * 2048;
      gl_lds16(attn + (m0 + sr) * 1024 + kc + gseg, Al + lo + (wid * 16) * 32);
      gl_lds16(wot + (n0 + sr) * 1024 + kc + gseg, Bl + lo + (wid * 16) * 32);
    }
    __syncthreads();

#pragma unroll
    for (int c = 0; c < 2; c++) {
      const int lo = c * 2048;
      bf16x8 af[2], bfr[2];
#pragma unroll
      for (int i = 0; i < 2; i++)
        af[i] = *(const bf16x8*)(&Al[lo + (wm + i * 16 + col) * 32 + fsg]);
#pragma unroll
      for (int j = 0; j < 2; j++)
        bfr[j] = *(const bf16x8*)(&Bl[lo + (wn + j * 16 + col) * 32 + fsg]);
#pragma unroll
      for (int i = 0; i < 2; i++)
#pragma unroll
        for (int j = 0; j < 2; j++)
          acc[i][j] = MFMA32(af[i], bfr[j], acc[i][j]);
    }
    __syncthreads();
  }

#pragma unroll
  for (int i = 0; i < 2; i++)
#pragma unroll
    for (int j = 0; j < 2; j++)
#pragma unroll
      for (int r = 0; r < 4; r++) {
        int m = m0 + wm + i * 16 + quad * 4 + r;
        int n = n0 + wn + j * 16 + col;
        out[m * 1024 + n] = acc[i][j][r] + bo[n];
      }
}

// ---------------- launch ----------------
extern "C" void kernel_launch(void* const* d_in, const int* in_sizes, int n_in,
                              void* d_out, int out_size, void* d_ws, size_t ws_size,
                              hipStream_t stream) {
  const float* x = (const float*)d_in[0];
  const float* Wqkv = (const float*)d_in[1];
  const float* Wo = (const float*)d_in[2];
  const float* bo = (const float*)d_in[3];
  float* out = (float*)d_out;

  unsigned short* qws = (unsigned short*)d_ws;   // [32][2048][64]      8.4 MB
  unsigned short* kws = qws + 4194304;           // [32][2048][64]      8.4 MB
  unsigned short* vws = kws + 4194304;           // [32][64][2048]      8.4 MB
  unsigned short* xb  = vws + 4194304;           // [4096][1024] (dead after qkv)
  unsigned short* aws = xb;                      //   reused: attn out [4096][1024]
  unsigned short* wqt = xb + 4194304;            // [3072][1024]        6.3 MB
  unsigned short* wot = wqt + 3145728;           // [1024][1024]        2.1 MB

  prep_kernel<<<3072, 256, 0, stream>>>(x, Wqkv, Wo, xb, wqt, wot);
  qkv_rope_kernel<<<dim3(24, 64), 256, 0, stream>>>(xb, wqt, qws, kws, vws);
  attn_kernel<<<dim3(32, 32), 256, 0, stream>>>(qws, kws, vws, aws);
  out_proj_kernel<<<dim3(16, 64), 256, 0, stream>>>(aws, wot, bo, out);
}